// Round 14
// baseline (175.916 us; speedup 1.0000x reference)
//
#include <hip/hip_runtime.h>

#define N_NODES 100000
#define N_EDGES 1600000
#define VOCAB   1000
#define EMB_DIM 64
#define OUT_DIM 32

#define BKT_BITS 9
#define BKT_SIZE 512
#define NBKT ((N_NODES + BKT_SIZE - 1) / BKT_SIZE)     // 196
#define CAP  10240                                     // per-bucket capacity (mean 8163)
#define NSB  512                                       // scatter blocks
#define STPB 512                                       // scatter threads
#define CHUNK (N_EDGES / NSB)                          // 3125 exact
#define NPART NBKT                                     // coeff partials (SPLIT=1)
#define NRF_BLOCKS 250                                 // reduce+final blocks

__device__ __forceinline__ void fatomic_add(float* p, float v) {
    unsafeAtomicAdd(p, v);   // ds_add_f32 / global_atomic_add_f32, no return
}

// ---- K0: zero cursors + ticket --------------------------------------------
__global__ void k_init(int* __restrict__ cursors, int* __restrict__ done) {
    int i = threadIdx.x;
    if (i < NBKT) cursors[i] = 0;
    if (i == NBKT) *done = 0;
}

// ---- K1: LDS counting-sort scatter; wave-scan; coalesced segment writes ---
// record: x = (row<<9) | local_col, y = w_bits ; keyed by col>>9
__global__ void __launch_bounds__(STPB) k_scatter(
        const int* __restrict__ row, const int* __restrict__ col,
        const float* __restrict__ w, int* __restrict__ cursors,
        uint2* __restrict__ recs) {
    __shared__ uint2 stage[CHUNK];                 // 25.0 KB
    __shared__ unsigned char seg[CHUNK];           //  3.1 KB
    __shared__ int cnt[NBKT], lofs[NBKT], gbase[NBKT];
    const int tid = threadIdx.x;
    const int e0 = blockIdx.x * CHUNK;

    for (int i = tid; i < NBKT; i += STPB) cnt[i] = 0;
    __syncthreads();
    // count
    for (int i = tid; i < CHUNK; i += STPB)
        atomicAdd(&cnt[col[e0 + i] >> BKT_BITS], 1);
    __syncthreads();
    // single-wave exclusive scan over 196 counters (4 per lane + shfl scan)
    if (tid < 64) {
        const int b4 = tid * 4;
        int c0 = (b4 + 0 < NBKT) ? cnt[b4 + 0] : 0;
        int c1 = (b4 + 1 < NBKT) ? cnt[b4 + 1] : 0;
        int c2 = (b4 + 2 < NBKT) ? cnt[b4 + 2] : 0;
        int c3 = (b4 + 3 < NBKT) ? cnt[b4 + 3] : 0;
        int s0 = c0, s1 = s0 + c1, s2 = s1 + c2, s3 = s2 + c3;
        int sc = s3;
        #pragma unroll
        for (int d = 1; d < 64; d <<= 1) {
            int o = __shfl_up(sc, d, 64);
            if (tid >= d) sc += o;
        }
        const int excl = sc - s3;
        if (b4 + 0 < NBKT) { lofs[b4+0] = excl;      gbase[b4+0] = (b4+0)*CAP + atomicAdd(&cursors[b4+0], c0); cnt[b4+0] = 0; }
        if (b4 + 1 < NBKT) { lofs[b4+1] = excl + s0; gbase[b4+1] = (b4+1)*CAP + atomicAdd(&cursors[b4+1], c1); cnt[b4+1] = 0; }
        if (b4 + 2 < NBKT) { lofs[b4+2] = excl + s1; gbase[b4+2] = (b4+2)*CAP + atomicAdd(&cursors[b4+2], c2); cnt[b4+2] = 0; }
        if (b4 + 3 < NBKT) { lofs[b4+3] = excl + s2; gbase[b4+3] = (b4+3)*CAP + atomicAdd(&cursors[b4+3], c3); cnt[b4+3] = 0; }
    }
    __syncthreads();
    // reorder into LDS stage, sorted by bucket
    for (int i = tid; i < CHUNK; i += STPB) {
        int c = col[e0 + i];                                      // L2-warm reread
        int r = row[e0 + i];
        int b = c >> BKT_BITS;
        int p = lofs[b] + atomicAdd(&cnt[b], 1);
        stage[p] = make_uint2(((unsigned)r << BKT_BITS) | (unsigned)(c & (BKT_SIZE - 1)),
                              __float_as_uint(w[e0 + i]));
        seg[p] = (unsigned char)b;
    }
    __syncthreads();
    // coalesced writeout: consecutive i -> consecutive dst within a segment
    for (int i = tid; i < CHUNK; i += STPB) {
        int b = seg[i];
        recs[gbase[b] + (i - lofs[b])] = stage[i];
    }
}

// ---- K2: per bucket: deg accumulate -> disseq = {rsqrt(1+deg), seq} -------
__global__ void __launch_bounds__(1024) k_dis(
        const uint2* __restrict__ recs, const int* __restrict__ cursors,
        const int* __restrict__ node_seq, uint2* __restrict__ disseq) {
    __shared__ float acc[BKT_SIZE];
    const int b = blockIdx.x;
    if (threadIdx.x < BKT_SIZE) acc[threadIdx.x] = 0.0f;
    __syncthreads();
    const int base = b * CAP;
    const int cnt = cursors[b];
    for (int i = threadIdx.x; i < cnt; i += 1024) {
        uint2 r = recs[base + i];
        fatomic_add(&acc[r.x & (BKT_SIZE - 1)], __uint_as_float(r.y));
    }
    __syncthreads();
    const int n0 = b << BKT_BITS;
    if (threadIdx.x < BKT_SIZE) {
        int n = n0 + threadIdx.x;
        if (n < N_NODES)
            disseq[n] = make_uint2(__float_as_uint(__frsqrt_rn(1.0f + acc[threadIdx.x])),
                                   (unsigned)node_seq[n]);
    }
}

// ---- K3: per bucket: vocab histogram; 1 8B gather per edge ----------------
__global__ void __launch_bounds__(1024) k_coeff(
        const uint2* __restrict__ recs, const int* __restrict__ cursors,
        const uint2* __restrict__ disseq, float* __restrict__ gcoeff) {
    __shared__ float dloc[BKT_SIZE];
    __shared__ float lc[VOCAB];
    const int b = blockIdx.x;
    const int n0 = b << BKT_BITS;
    if (threadIdx.x < VOCAB) lc[threadIdx.x] = 0.0f;
    if (threadIdx.x < BKT_SIZE) {
        int n = n0 + threadIdx.x;
        dloc[threadIdx.x] = (n < N_NODES) ? __uint_as_float(disseq[n].x) : 0.0f;
    }
    __syncthreads();
    const int base = b * CAP;
    const int cnt = cursors[b];
    for (int i = threadIdx.x; i < cnt; i += 1024) {
        uint2 rec = recs[base + i];
        int lcol = rec.x & (BKT_SIZE - 1);
        int r    = rec.x >> BKT_BITS;
        uint2 ds = disseq[r];                                     // 8B L2 gather
        fatomic_add(&lc[ds.y],
            __uint_as_float(ds.x) * __uint_as_float(rec.y) * dloc[lcol]);
    }
    if (threadIdx.x < BKT_SIZE) {                                 // self loops
        int n = n0 + threadIdx.x;
        if (n < N_NODES) {
            uint2 ds = disseq[n];
            float d = __uint_as_float(ds.x);
            fatomic_add(&lc[ds.y], d * d);
        }
    }
    __syncthreads();
    if (threadIdx.x < VOCAB)
        gcoeff[b * VOCAB + threadIdx.x] = lc[threadIdx.x];
}

// ---- K4: reduce partials -> coeff; fold into per-block tpart; last -> out -
__global__ void __launch_bounds__(256) k_reduce_final(
        const float* __restrict__ gcoeff, const float* __restrict__ emb,
        const float* __restrict__ W, const float* __restrict__ bias,
        float* __restrict__ tpart, int* __restrict__ done,
        float* __restrict__ out) {
    __shared__ float tk[EMB_DIM];
    __shared__ int lastflag;
    const int tid = threadIdx.x;
    const int l = tid & 63;
    if (tid < EMB_DIM) tk[tid] = 0.0f;
    __syncthreads();
    {   // 4 vocab slots per block (one per wave)
        const int v = (blockIdx.x * 256 + tid) >> 6;              // 0..999
        float s = 0.0f;
        for (int p = l; p < NPART; p += 64) s += gcoeff[p * VOCAB + v];
        for (int off = 32; off > 0; off >>= 1) s += __shfl_down(s, off, 64);
        float cv = __shfl(s, 0, 64);                              // coeff[v]
        fatomic_add(&tk[l], cv * emb[v * EMB_DIM + l]);           // LDS, 4-way
    }
    __syncthreads();
    if (tid < EMB_DIM) tpart[blockIdx.x * EMB_DIM + tid] = tk[tid];
    __syncthreads();
    if (tid == 0) {
        __threadfence();                                          // release tpart row
        lastflag = (atomicAdd(done, 1) == NRF_BLOCKS - 1) ? 1 : 0;
    }
    __syncthreads();
    if (lastflag) {
        __threadfence();                                          // acquire
        __shared__ float tk2[4][EMB_DIM];
        const int g = tid >> 6;                                   // 0..3
        float s = 0.0f;
        for (int p = g; p < NRF_BLOCKS; p += 4)
            s += ((volatile float*)tpart)[p * EMB_DIM + l];
        tk2[g][l] = s;
        __syncthreads();
        if (tid < EMB_DIM)
            tk[tid] = tk2[0][tid] + tk2[1][tid] + tk2[2][tid] + tk2[3][tid];
        __syncthreads();
        if (tid < OUT_DIM) {
            float s2 = 0.0f;
            #pragma unroll
            for (int k = 0; k < EMB_DIM; ++k) s2 += tk[k] * W[k * OUT_DIM + tid];
            out[tid] = s2 * (1.0f / (float)N_NODES) + bias[tid];
        }
    }
}

extern "C" void kernel_launch(void* const* d_in, const int* in_sizes, int n_in,
                              void* d_out, int out_size, void* d_ws, size_t ws_size,
                              hipStream_t stream) {
    const int*   node_seq = (const int*)  d_in[0];
    const int*   eidx     = (const int*)  d_in[1];   // [2, E] flat
    const float* ew       = (const float*)d_in[2];
    const float* emb      = (const float*)d_in[3];
    const float* W        = (const float*)d_in[4];
    const float* bias     = (const float*)d_in[5];
    float*       out      = (float*)d_out;

    const int* row = eidx;
    const int* col = eidx + N_EDGES;

    char* wsb = (char*)d_ws;
    const size_t REC_BYTES = (size_t)NBKT * CAP * sizeof(uint2); // 16.05 MB
    uint2* recs    = (uint2*)wsb;
    int*   cursors = (int*)(wsb + REC_BYTES);                    // NBKT ints
    int*   done    = cursors + NBKT;
    uint2* disseq  = (uint2*)(wsb + REC_BYTES + 4096);
    float* gcoeff  = (float*)(disseq + N_NODES);                 // NPART*VOCAB
    float* tpart   = gcoeff + (size_t)NPART * VOCAB;             // NRF_BLOCKS*64

    k_init<<<1, 256, 0, stream>>>(cursors, done);
    k_scatter<<<NSB, STPB, 0, stream>>>(row, col, ew, cursors, recs);
    k_dis<<<NBKT, 1024, 0, stream>>>(recs, cursors, node_seq, disseq);
    k_coeff<<<NBKT, 1024, 0, stream>>>(recs, cursors, disseq, gcoeff);
    k_reduce_final<<<NRF_BLOCKS, 256, 0, stream>>>(gcoeff, emb, W, bias,
                                                   tpart, done, out);
}